// Round 11
// baseline (79.371 us; speedup 1.0000x reference)
//
#include <hip/hip_runtime.h>

#define DEVFN static __device__ __forceinline__

constexpr int kLtot = 1024, kC = 32, kB = 2;
constexpr int kG = 64;                 // chunks per chain
constexpr int kCL = kLtot / kG;        // 16 steps per chunk
constexpr int kNCH = kB * kC;          // 64 chains
constexpr int kNCK = kNCH * kG;        // 4096 chunks

// phase1 per-wave LDS: THREE 2048B A-slots (ring-3: 2 steps of DMA in flight) + 144B v-row
constexpr int kRing = 3;
constexpr int kSlotB = 2048;
constexpr int kWaveB = kRing * kSlotB + 144;  // 6288

typedef int v2i __attribute__((ext_vector_type(2)));
typedef __attribute__((ext_vector_type(4))) float f32x4;
typedef __attribute__((ext_vector_type(8))) short s16x8;

union BFrag { unsigned u[4]; s16x8 v; };

DEVFN void gload16(const void* g, void* l) {
  __builtin_amdgcn_global_load_lds((const __attribute__((address_space(1))) void*)g,
                                   (__attribute__((address_space(3))) void*)l, 16, 0, 0);
}

// xor-16 via ds_swizzle (DS pipe), xor-32 via permlane32_swap (R3/R6-proven combo)
DEVFN float redpair16(float x) {
  return x + __int_as_float(__builtin_amdgcn_ds_swizzle(__float_as_int(x), 0x401F));
}
DEVFN float redpair32(float x) {
#if __has_builtin(__builtin_amdgcn_permlane32_swap)
  v2i r = __builtin_amdgcn_permlane32_swap(__float_as_int(x), __float_as_int(x), false, false);
  return __int_as_float(r.x) + __int_as_float(r.y);
#else
  return x + __shfl_xor(x, 32);
#endif
}
DEVFN float redq(float x) { return redpair32(redpair16(x)); }

// split two f32 into packed bf16 hi + packed bf16 lo (residual), RNE via v_cvt_pk_bf16_f32
DEVFN void splitpk(float x0, float x1, unsigned& h, unsigned& l) {
  unsigned hh, ll;
  asm("v_cvt_pk_bf16_f32 %0, %1, %2" : "=v"(hh) : "v"(x0), "v"(x1));
  const float b0 = __uint_as_float(hh << 16);
  const float b1 = __uint_as_float(hh & 0xffff0000u);
  const float s0 = x0 - b0, s1 = x1 - b1;
  asm("v_cvt_pk_bf16_f32 %0, %1, %2" : "=v"(ll) : "v"(s0), "v"(s1));
  h = hh; l = ll;
}

DEVFN f32x4 mfma16(const unsigned a[4], const unsigned b[4], f32x4 c) {
  BFrag A, B;
  A.u[0] = a[0]; A.u[1] = a[1]; A.u[2] = a[2]; A.u[3] = a[3];
  B.u[0] = b[0]; B.u[1] = b[1]; B.u[2] = b[2]; B.u[3] = b[3];
  return __builtin_amdgcn_mfma_f32_16x16x32_bf16(A.v, B.v, c, 0, 0, 0);
}

// assemble word w (literal!) of the B-fragments from this lane's k-slice values.
// B1 = [Pr; -Pi] (q<2 lanes take Pr; q>=2 take -Pi), B2 = [Pi; Pr].
#define PUTW(w, r0_, r1_, i0_, i1_)                                \
  do {                                                             \
    unsigned rh_, rl_, ih_, il_;                                   \
    splitpk((r0_), (r1_), rh_, rl_);                               \
    splitpk((i0_), (i1_), ih_, il_);                               \
    b1h[w] = loQ ? rh_ : (ih_ ^ 0x80008000u);                      \
    b1l[w] = loQ ? rl_ : (il_ ^ 0x80008000u);                      \
    b2h[w] = loQ ? ih_ : rh_;                                      \
    b2l[w] = loQ ? il_ : rl_;                                      \
  } while (0)

// ---------------- Phase 1: chunk transition P_g + response v_g (MFMA engine, ring-3) ---------
// 1 chunk per wave, 4 waves/block. P-product via mfma_f32_16x16x32_bf16 with complex K-packing
// ([Ar|Ai] x [Pr;-Pi] / [Pi;Pr]) and 2-term bf16 hi/lo split (3 MFMA per accumulator).
// Ring-3 gload_lds staging (2 steps in flight, counted vmcnt(8)); A(t+1) pre-split at end of
// iteration t so the splitpk work is OFF the serial P-chain. v_g via the proven fp32 side-path.
__global__ __launch_bounds__(256, 4) void pscan_phase1(
    const float* __restrict__ Ar, const float* __restrict__ Ai,
    const float* __restrict__ Xr, const float* __restrict__ Xi,
    float* __restrict__ Pg, float* __restrict__ Vg) {
  __shared__ __align__(16) float ldsF[4 * (kWaveB / 4)];
  const int lane = threadIdx.x & 63;
  const int wid = threadIdx.x >> 6;
  const int q = lane >> 4, j = lane & 15, h = q & 1;
  const bool loQ = (q < 2);
  const int kq = q, ka = (lane >> 2) & 3, kc = lane & 3;
  const int jv = 4 * kc + ka;

  const int ck = blockIdx.x * 4 + wid;
  const int chain = ck >> 6, g = ck & 63;
  const int bb = chain >> 5, cc = chain & 31;
  const int t0 = g * kCL;

  char* ldsW = (char*)ldsF + wid * kWaveB;
  char* pbase = ldsW + kRing * kSlotB;
  const int aOff = (q >> 1) * 1024 + j * 64 + h * 32;  // MFMA A-frag: row j, 8 cols, plane q>>1
  const int laneAv = ka * 64 + kq * 16 + kc * 256;     // v-path: A[jv][4kq..], plane-relative

  const size_t aBase = ((size_t)(bb * kLtot + t0) * kC + cc) * 256;
  const size_t xBase2 = ((size_t)(bb * kLtot + t0) * kC + cc) * 16;
  const size_t aStep = (size_t)kC * 256, xStep = (size_t)kC * 16;
  const float* arPtr = Ar + aBase + (size_t)lane * 4;
  const float* aiPtr = Ai + aBase + (size_t)lane * 4;
  const float* xrPtr = Xr + xBase2 + jv;
  const float* xiPtr = Xi + xBase2 + jv;

  char* vwA = pbase + jv * 8;          // v write (kq==0 lanes only)
  const char* vrA = pbase + kq * 32;   // v read slice

  float xrP[3], xiP[3];
  auto issueStep = [&](int t) {        // exactly 4 vmem ops, always
    char* sd = ldsW + (t % 3) * kSlotB;
    gload16(arPtr + (size_t)t * aStep, sd);
    gload16(aiPtr + (size_t)t * aStep, sd + 1024);
    xrP[t % 3] = xrPtr[(size_t)t * xStep];
    xiP[t % 3] = xiPtr[(size_t)t * xStep];
  };

  issueStep(0);
  asm volatile("" ::: "memory");
  issueStep(1);
  asm volatile("" ::: "memory");
  issueStep(2);
  asm volatile("" ::: "memory");

  unsigned b1h[4], b1l[4], b2h[4], b2l[4];   // B-fragments of current P (hi/lo, B1/B2)
  unsigned Ah[4], Al[4];                     // pre-split A-fragment of the CURRENT step
  f32x4 accR, accI;                          // P in MFMA C-layout after each step
  float vre[4], vim[4], vnr, vni;

  // ---- init: P = A_0 (column reads -> B-frags), v = x_0 (staged xrP + v-exchange) ----
  asm volatile("s_waitcnt vmcnt(8)" ::: "memory");  // step-0 tile + x resident
  {
    const char* s0 = ldsW;
    float R[8], I[8];
#pragma unroll
    for (int e = 0; e < 8; ++e) {
      R[e] = *(const float*)(s0 + (8 * h + e) * 64 + j * 4);
      I[e] = *(const float*)(s0 + 1024 + (8 * h + e) * 64 + j * 4);
    }
    PUTW(0, R[0], R[1], I[0], I[1]);
    PUTW(1, R[2], R[3], I[2], I[3]);
    PUTW(2, R[4], R[5], I[4], I[5]);
    PUTW(3, R[6], R[7], I[6], I[7]);
    vnr = xrP[0]; vni = xiP[0];
    if (kq == 0) *(float2*)vwA = make_float2(vnr, vni);
    const float4 v0 = *(const float4*)(vrA);
    const float4 v1 = *(const float4*)(vrA + 16);
    vre[0] = v0.x; vim[0] = v0.y; vre[1] = v0.z; vim[1] = v0.w;
    vre[2] = v1.x; vim[2] = v1.y; vre[3] = v1.z; vim[3] = v1.w;
  }
  asm volatile("s_waitcnt lgkmcnt(0)" ::: "memory");  // slot-0 reads done before re-staging
  issueStep(3);                                       // -> slot 0
  asm volatile("s_waitcnt vmcnt(8)" ::: "memory");    // step-1 resident (outstanding: 2,3)

  auto splitA = [&](int sl) {  // pre-split A-fragment of slot sl into Ah/Al
    const char* sb = ldsW + sl * kSlotB;
    const float4 a0 = *(const float4*)(sb + aOff);
    const float4 a1 = *(const float4*)(sb + aOff + 16);
    splitpk(a0.x, a0.y, Ah[0], Al[0]);
    splitpk(a0.z, a0.w, Ah[1], Al[1]);
    splitpk(a1.x, a1.y, Ah[2], Al[2]);
    splitpk(a1.z, a1.w, Ah[3], Al[3]);
  };
  splitA(1);

  auto stepMFMA = [&](int sl) {  // P update (pre-split A) + v side-path (tile sl, x sl)
    const f32x4 zz = {0.f, 0.f, 0.f, 0.f};
    accR = mfma16(Al, b1h, zz);
    accI = mfma16(Al, b2h, zz);
    accR = mfma16(Ah, b1l, accR);
    accI = mfma16(Ah, b2l, accI);
    accR = mfma16(Ah, b1h, accR);
    accI = mfma16(Ah, b2h, accI);
    {
      const char* sb = ldsW + sl * kSlotB;
      const float4 a4 = *(const float4*)(sb + laneAv);
      const float4 b4 = *(const float4*)(sb + laneAv + 1024);
      float pr = a4.x * vre[0] - b4.x * vim[0];
      float pi = a4.x * vim[0] + b4.x * vre[0];
      pr += a4.y * vre[1] - b4.y * vim[1];  pi += a4.y * vim[1] + b4.y * vre[1];
      pr += a4.z * vre[2] - b4.z * vim[2];  pi += a4.z * vim[2] + b4.z * vre[2];
      pr += a4.w * vre[3] - b4.w * vim[3];  pi += a4.w * vim[3] + b4.w * vre[3];
      pr = redq(pr); pi = redq(pi);
      vnr = pr + xrP[sl];
      vni = pi + xiP[sl];
      if (kq == 0) *(float2*)vwA = make_float2(vnr, vni);
      const float4 v0 = *(const float4*)(vrA);
      const float4 v1 = *(const float4*)(vrA + 16);
      vre[0] = v0.x; vim[0] = v0.y; vre[1] = v0.z; vim[1] = v0.w;
      vre[2] = v1.x; vim[2] = v1.y; vre[3] = v1.z; vim[3] = v1.w;
    }
  };

  auto repack = [&]() {  // C-layout acc -> next step's B-frags (16 shfl)
    const int srcA = j | ((2 * h) << 4);
    const int srcB = srcA + 16;
    PUTW(0, __shfl(accR[0], srcA), __shfl(accR[1], srcA), __shfl(accI[0], srcA), __shfl(accI[1], srcA));
    PUTW(1, __shfl(accR[2], srcA), __shfl(accR[3], srcA), __shfl(accI[2], srcA), __shfl(accI[3], srcA));
    PUTW(2, __shfl(accR[0], srcB), __shfl(accR[1], srcB), __shfl(accI[0], srcB), __shfl(accI[1], srcB));
    PUTW(3, __shfl(accR[2], srcB), __shfl(accR[3], srcB), __shfl(accI[2], srcB), __shfl(accI[3], srcB));
  };

  // steady state entering iter t: tiles <= t resident; DMA of t+1, t+2 in flight (8 ops)
#pragma unroll 3
  for (int t = 1; t <= kCL - 4; ++t) {   // t = 1..12, issues 4..15
    stepMFMA(t % 3);
    repack();
    issueStep(t + 3);                               // -> slot t%3 (tile t just consumed)
    asm volatile("s_waitcnt vmcnt(8)" ::: "memory");  // tile t+1 resident
    splitA((t + 1) % 3);                            // off-critical-path pre-split
  }
  // t = 13
  stepMFMA(1);
  repack();
  asm volatile("s_waitcnt vmcnt(4)" ::: "memory");  // tile 14 resident
  splitA(2);
  // t = 14
  stepMFMA(2);
  repack();
  asm volatile("s_waitcnt vmcnt(0)" ::: "memory");  // tile 15 resident
  splitA(0);
  // t = 15 (final; acc = P_g, vnr/vni = v_g)
  stepMFMA(0);

  // ---- store P_g (row-major [row][col] float2) from C-layout, and v_g ----
  {
    float* pd = Pg + (size_t)ck * 512;
#pragma unroll
    for (int r = 0; r < 4; ++r) {
      *(float2*)(pd + (4 * q + r) * 32 + j * 2) = make_float2(accR[r], accI[r]);
    }
  }
  if (kq == 0) *(float2*)(Vg + (size_t)ck * 32 + jv * 2) = make_float2(vnr, vni);
}

// ---------------- Phase 2: sequential carry scan (1 chain per wave, 64-lane matvec) ----------
constexpr int kD2 = 4;
__global__ __launch_bounds__(64, 1) void pscan_phase2(
    const float* __restrict__ Pg, const float* __restrict__ Vg, float* __restrict__ Sg) {
  const int lane = threadIdx.x;
  const int kq = lane >> 4, i = lane & 15;
  const int chain = blockIdx.x;

  const float* pB = Pg + (size_t)chain * kG * 512 + (size_t)i * 32 + 8 * kq;
  const float* vB = Vg + (size_t)chain * kG * 32 + 2 * i;
  float* sB = Sg + (size_t)chain * kG * 32 + 2 * i;

  float4 bP0[kD2], bP1[kD2]; float2 bV[kD2];
#pragma unroll
  for (int d = 0; d < kD2; ++d) {
    bP0[d] = *(const float4*)(pB + (size_t)d * 512);
    bP1[d] = *(const float4*)(pB + (size_t)d * 512 + 4);
    bV[d] = *(const float2*)(vB + (size_t)d * 32);
  }

  float ykr[4] = {0, 0, 0, 0}, yki[4] = {0, 0, 0, 0};
  float ynr = 0.f, yni = 0.f;

  for (int gg = 0; gg < kG; gg += kD2) {
#pragma unroll
    for (int d = 0; d < kD2; ++d) {
      if (kq == 0) *(float2*)(sB + (size_t)(gg + d) * 32) = make_float2(ynr, yni);  // S_{g-1}
      const float4 p0 = bP0[d], p1 = bP1[d];
      const float2 vv = bV[d];
      const int gn = gg + d + kD2;
      if (gn < kG) {
        bP0[d] = *(const float4*)(pB + (size_t)gn * 512);
        bP1[d] = *(const float4*)(pB + (size_t)gn * 512 + 4);
        bV[d] = *(const float2*)(vB + (size_t)gn * 32);
      }
      float tr = p0.x * ykr[0] - p0.y * yki[0] + p0.z * ykr[1] - p0.w * yki[1]
               + p1.x * ykr[2] - p1.y * yki[2] + p1.z * ykr[3] - p1.w * yki[3];
      float ti = p0.x * yki[0] + p0.y * ykr[0] + p0.z * yki[1] + p0.w * ykr[1]
               + p1.x * yki[2] + p1.y * ykr[2] + p1.z * yki[3] + p1.w * ykr[3];
      tr = redq(tr); ti = redq(ti);
      ynr = tr + vv.x;
      yni = ti + vv.y;
#pragma unroll
      for (int kk = 0; kk < 4; ++kk) {
        const int src = (lane & 48) | (4 * kq + kk);
        ykr[kk] = __shfl(ynr, src);
        yki[kk] = __shfl(yni, src);
      }
    }
  }
}

// ---------------- Phase 3: replay chunks from carries (64-lane matvec, high occupancy) ----------
__global__ __launch_bounds__(256, 4) void pscan_phase3(
    const float* __restrict__ Ar, const float* __restrict__ Ai,
    const float* __restrict__ Xr, const float* __restrict__ Xi,
    const float* __restrict__ Sg, float* __restrict__ out) {
  const int lane = threadIdx.x & 63;
  const int wid = threadIdx.x >> 6;
  const int kq = lane >> 4, i = lane & 15;
  const int ck = blockIdx.x * 4 + wid;
  const int chain = ck >> 6, g = ck & 63;
  const int bb = chain >> 5, cc = chain & 31;
  const int t0 = g * kCL;

  const size_t aBase = ((size_t)(bb * kLtot + t0) * kC + cc) * 256 + (size_t)i * 16 + 4 * kq;
  const size_t xBase = ((size_t)(bb * kLtot + t0) * kC + cc) * 16 + i;
  const size_t aStep = (size_t)kC * 256, xStep = (size_t)kC * 16;
  float* outB = out + ((size_t)(bb * kLtot + t0) * kC + cc) * 32 + 2 * i;

  float ynr, yni, ykr[4], yki[4];
  {
    const float2 s = *(const float2*)(Sg + (size_t)ck * 32 + 2 * i);
    ynr = s.x; yni = s.y;
  }
#pragma unroll
  for (int kk = 0; kk < 4; ++kk) {
    const int src = (lane & 48) | (4 * kq + kk);
    ykr[kk] = __shfl(ynr, src);
    yki[kk] = __shfl(yni, src);
  }

  float4 aR[2], aI[2]; float2 xx[2];
  auto loadT = [&](int t, int s) {
    aR[s] = *(const float4*)(Ar + aBase + (size_t)t * aStep);
    aI[s] = *(const float4*)(Ai + aBase + (size_t)t * aStep);
    xx[s].x = Xr[xBase + (size_t)t * xStep];
    xx[s].y = Xi[xBase + (size_t)t * xStep];
  };
  loadT(0, 0);
  loadT(1, 1);

  for (int t = 0; t < kCL; ++t) {
    const int s = t & 1;
    const float4 a4 = aR[s], b4 = aI[s];
    const float2 xv = xx[s];
    float tr = a4.x * ykr[0] - b4.x * yki[0] + a4.y * ykr[1] - b4.y * yki[1]
             + a4.z * ykr[2] - b4.z * yki[2] + a4.w * ykr[3] - b4.w * yki[3];
    float ti = a4.x * yki[0] + b4.x * ykr[0] + a4.y * yki[1] + b4.y * ykr[1]
             + a4.z * yki[2] + b4.z * ykr[2] + a4.w * yki[3] + b4.w * ykr[3];
    tr = redq(tr); ti = redq(ti);
    ynr = tr + xv.x;
    yni = ti + xv.y;
    if (kq == 0) *(float2*)(outB + (size_t)t * (kC * 32)) = make_float2(ynr, yni);
    const int tn = t + 2;
    if (tn < kCL) loadT(tn, s);
#pragma unroll
    for (int kk = 0; kk < 4; ++kk) {
      const int src = (lane & 48) | (4 * kq + kk);
      ykr[kk] = __shfl(ynr, src);
      yki[kk] = __shfl(yni, src);
    }
  }
}

extern "C" void kernel_launch(void* const* d_in, const int* in_sizes, int n_in,
                              void* d_out, int out_size, void* d_ws, size_t ws_size,
                              hipStream_t stream) {
  const float* Ar = (const float*)d_in[0];
  const float* Ai = (const float*)d_in[1];
  const float* Xr = (const float*)d_in[2];
  const float* Xi = (const float*)d_in[3];
  // Workspace: Pg 8MB + Vg 512KB + Sg 512KB = 9MB
  float* Pg = (float*)d_ws;
  float* Vg = Pg + (size_t)kNCK * 512;
  float* Sg = Vg + (size_t)kNCK * 32;

  pscan_phase1<<<kNCK / 4, 256, 0, stream>>>(Ar, Ai, Xr, Xi, Pg, Vg);
  pscan_phase2<<<kNCH, 64, 0, stream>>>(Pg, Vg, Sg);
  pscan_phase3<<<kNCK / 4, 256, 0, stream>>>(Ar, Ai, Xr, Xi, Sg, (float*)d_out);
}

// Round 12
// 78.865 us; speedup vs baseline: 1.0064x; 1.0064x over previous
//
#include <hip/hip_runtime.h>

#define DEVFN static __device__ __forceinline__

constexpr int kLtot = 1024, kC = 32, kB = 2;
constexpr int kG = 64;                 // chunks per chain
constexpr int kCL = kLtot / kG;        // 16 steps per chunk
constexpr int kNCH = kB * kC;          // 64 chains
constexpr int kNCK = kNCH * kG;        // 4096 chunks

// phase1 per-wave LDS: THREE 2048B A-slots (ring-3: 2 steps of DMA in flight) + 144B v-row
constexpr int kRing = 3;
constexpr int kSlotB = 2048;
constexpr int kWaveB = kRing * kSlotB + 144;  // 6288

typedef int v2i __attribute__((ext_vector_type(2)));
typedef __attribute__((ext_vector_type(4))) float f32x4;
typedef __attribute__((ext_vector_type(8))) short s16x8;

union BFrag { unsigned u[4]; s16x8 v; };

DEVFN void gload16(const void* g, void* l) {
  __builtin_amdgcn_global_load_lds((const __attribute__((address_space(1))) void*)g,
                                   (__attribute__((address_space(3))) void*)l, 16, 0, 0);
}

// xor-16 via ds_swizzle (DS pipe), xor-32 via permlane32_swap (R3/R6-proven combo)
DEVFN float redpair16(float x) {
  return x + __int_as_float(__builtin_amdgcn_ds_swizzle(__float_as_int(x), 0x401F));
}
DEVFN float redpair32(float x) {
#if __has_builtin(__builtin_amdgcn_permlane32_swap)
  v2i r = __builtin_amdgcn_permlane32_swap(__float_as_int(x), __float_as_int(x), false, false);
  return __int_as_float(r.x) + __int_as_float(r.y);
#else
  return x + __shfl_xor(x, 32);
#endif
}
DEVFN float redq(float x) { return redpair32(redpair16(x)); }

// split two f32 into packed bf16 hi + packed bf16 lo (residual), RNE via v_cvt_pk_bf16_f32
DEVFN void splitpk(float x0, float x1, unsigned& h, unsigned& l) {
  unsigned hh, ll;
  asm("v_cvt_pk_bf16_f32 %0, %1, %2" : "=v"(hh) : "v"(x0), "v"(x1));
  const float b0 = __uint_as_float(hh << 16);
  const float b1 = __uint_as_float(hh & 0xffff0000u);
  const float s0 = x0 - b0, s1 = x1 - b1;
  asm("v_cvt_pk_bf16_f32 %0, %1, %2" : "=v"(ll) : "v"(s0), "v"(s1));
  h = hh; l = ll;
}

DEVFN f32x4 mfma16(const unsigned a[4], const unsigned b[4], f32x4 c) {
  BFrag A, B;
  A.u[0] = a[0]; A.u[1] = a[1]; A.u[2] = a[2]; A.u[3] = a[3];
  B.u[0] = b[0]; B.u[1] = b[1]; B.u[2] = b[2]; B.u[3] = b[3];
  return __builtin_amdgcn_mfma_f32_16x16x32_bf16(A.v, B.v, c, 0, 0, 0);
}

// assemble word w (literal!) of the B-fragments from this lane's k-slice values.
// B1 = [Pr; -Pi] (q<2 lanes take Pr; q>=2 take -Pi), B2 = [Pi; Pr].
#define PUTW(w, r0_, r1_, i0_, i1_)                                \
  do {                                                             \
    unsigned rh_, rl_, ih_, il_;                                   \
    splitpk((r0_), (r1_), rh_, rl_);                               \
    splitpk((i0_), (i1_), ih_, il_);                               \
    b1h[w] = loQ ? rh_ : (ih_ ^ 0x80008000u);                      \
    b1l[w] = loQ ? rl_ : (il_ ^ 0x80008000u);                      \
    b2h[w] = loQ ? ih_ : rh_;                                      \
    b2l[w] = loQ ? il_ : rl_;                                      \
  } while (0)

// ---------------- Phase 1: chunk transition P_g + response v_g (MFMA engine, ring-3) ---------
// 1 chunk per wave, 4 waves/block. P-product via mfma_f32_16x16x32_bf16 with complex K-packing
// ([Ar|Ai] x [Pr;-Pi] / [Pi;Pr]) and 2-term bf16 hi/lo split (3 MFMA per accumulator).
// Ring-3 gload_lds staging (2 steps in flight, counted vmcnt(8)); A(t+1) pre-split at end of
// iteration t so the splitpk work is OFF the serial P-chain. v_g via the proven fp32 side-path.
__global__ __launch_bounds__(256, 4) void pscan_phase1(
    const float* __restrict__ Ar, const float* __restrict__ Ai,
    const float* __restrict__ Xr, const float* __restrict__ Xi,
    float* __restrict__ Pg, float* __restrict__ Vg) {
  __shared__ __align__(16) float ldsF[4 * (kWaveB / 4)];
  const int lane = threadIdx.x & 63;
  const int wid = threadIdx.x >> 6;
  const int q = lane >> 4, j = lane & 15, h = q & 1;
  const bool loQ = (q < 2);
  const int kq = q, ka = (lane >> 2) & 3, kc = lane & 3;
  const int jv = 4 * kc + ka;

  const int ck = blockIdx.x * 4 + wid;
  const int chain = ck >> 6, g = ck & 63;
  const int bb = chain >> 5, cc = chain & 31;
  const int t0 = g * kCL;

  char* ldsW = (char*)ldsF + wid * kWaveB;
  char* pbase = ldsW + kRing * kSlotB;
  const int aOff = (q >> 1) * 1024 + j * 64 + h * 32;  // MFMA A-frag: row j, 8 cols, plane q>>1
  const int laneAv = ka * 64 + kq * 16 + kc * 256;     // v-path: A[jv][4kq..], plane-relative

  const size_t aBase = ((size_t)(bb * kLtot + t0) * kC + cc) * 256;
  const size_t xBase2 = ((size_t)(bb * kLtot + t0) * kC + cc) * 16;
  const size_t aStep = (size_t)kC * 256, xStep = (size_t)kC * 16;
  const float* arPtr = Ar + aBase + (size_t)lane * 4;
  const float* aiPtr = Ai + aBase + (size_t)lane * 4;
  const float* xrPtr = Xr + xBase2 + jv;
  const float* xiPtr = Xi + xBase2 + jv;

  char* vwA = pbase + jv * 8;          // v write (kq==0 lanes only)
  const char* vrA = pbase + kq * 32;   // v read slice

  float xrP[3], xiP[3];
  auto issueStep = [&](int t) {        // exactly 4 vmem ops, always
    char* sd = ldsW + (t % 3) * kSlotB;
    gload16(arPtr + (size_t)t * aStep, sd);
    gload16(aiPtr + (size_t)t * aStep, sd + 1024);
    xrP[t % 3] = xrPtr[(size_t)t * xStep];
    xiP[t % 3] = xiPtr[(size_t)t * xStep];
  };

  issueStep(0);
  asm volatile("" ::: "memory");
  issueStep(1);
  asm volatile("" ::: "memory");
  issueStep(2);
  asm volatile("" ::: "memory");

  unsigned b1h[4], b1l[4], b2h[4], b2l[4];   // B-fragments of current P (hi/lo, B1/B2)
  unsigned Ah[4], Al[4];                     // pre-split A-fragment of the CURRENT step
  f32x4 accR, accI;                          // P in MFMA C-layout after each step
  float vre[4], vim[4], vnr, vni;

  // ---- init: P = A_0 (column reads -> B-frags), v = x_0 (staged xrP + v-exchange) ----
  asm volatile("s_waitcnt vmcnt(8)" ::: "memory");  // step-0 tile + x resident
  {
    const char* s0 = ldsW;
    float R[8], I[8];
#pragma unroll
    for (int e = 0; e < 8; ++e) {
      R[e] = *(const float*)(s0 + (8 * h + e) * 64 + j * 4);
      I[e] = *(const float*)(s0 + 1024 + (8 * h + e) * 64 + j * 4);
    }
    PUTW(0, R[0], R[1], I[0], I[1]);
    PUTW(1, R[2], R[3], I[2], I[3]);
    PUTW(2, R[4], R[5], I[4], I[5]);
    PUTW(3, R[6], R[7], I[6], I[7]);
    vnr = xrP[0]; vni = xiP[0];
    if (kq == 0) *(float2*)vwA = make_float2(vnr, vni);
    const float4 v0 = *(const float4*)(vrA);
    const float4 v1 = *(const float4*)(vrA + 16);
    vre[0] = v0.x; vim[0] = v0.y; vre[1] = v0.z; vim[1] = v0.w;
    vre[2] = v1.x; vim[2] = v1.y; vre[3] = v1.z; vim[3] = v1.w;
  }
  asm volatile("s_waitcnt lgkmcnt(0)" ::: "memory");  // slot-0 reads done before re-staging
  issueStep(3);                                       // -> slot 0
  asm volatile("s_waitcnt vmcnt(8)" ::: "memory");    // step-1 resident (outstanding: 2,3)

  auto splitA = [&](int sl) {  // pre-split A-fragment of slot sl into Ah/Al
    const char* sb = ldsW + sl * kSlotB;
    const float4 a0 = *(const float4*)(sb + aOff);
    const float4 a1 = *(const float4*)(sb + aOff + 16);
    splitpk(a0.x, a0.y, Ah[0], Al[0]);
    splitpk(a0.z, a0.w, Ah[1], Al[1]);
    splitpk(a1.x, a1.y, Ah[2], Al[2]);
    splitpk(a1.z, a1.w, Ah[3], Al[3]);
  };
  splitA(1);

  auto stepMFMA = [&](int sl) {  // P update (pre-split A) + v side-path (tile sl, x sl)
    const f32x4 zz = {0.f, 0.f, 0.f, 0.f};
    accR = mfma16(Al, b1h, zz);
    accI = mfma16(Al, b2h, zz);
    accR = mfma16(Ah, b1l, accR);
    accI = mfma16(Ah, b2l, accI);
    accR = mfma16(Ah, b1h, accR);
    accI = mfma16(Ah, b2h, accI);
    {
      const char* sb = ldsW + sl * kSlotB;
      const float4 a4 = *(const float4*)(sb + laneAv);
      const float4 b4 = *(const float4*)(sb + laneAv + 1024);
      float pr = a4.x * vre[0] - b4.x * vim[0];
      float pi = a4.x * vim[0] + b4.x * vre[0];
      pr += a4.y * vre[1] - b4.y * vim[1];  pi += a4.y * vim[1] + b4.y * vre[1];
      pr += a4.z * vre[2] - b4.z * vim[2];  pi += a4.z * vim[2] + b4.z * vre[2];
      pr += a4.w * vre[3] - b4.w * vim[3];  pi += a4.w * vim[3] + b4.w * vre[3];
      pr = redq(pr); pi = redq(pi);
      vnr = pr + xrP[sl];
      vni = pi + xiP[sl];
      if (kq == 0) *(float2*)vwA = make_float2(vnr, vni);
      const float4 v0 = *(const float4*)(vrA);
      const float4 v1 = *(const float4*)(vrA + 16);
      vre[0] = v0.x; vim[0] = v0.y; vre[1] = v0.z; vim[1] = v0.w;
      vre[2] = v1.x; vim[2] = v1.y; vre[3] = v1.z; vim[3] = v1.w;
    }
  };

  auto repack = [&]() {  // C-layout acc -> next step's B-frags (16 shfl)
    const int srcA = j | ((2 * h) << 4);
    const int srcB = srcA + 16;
    PUTW(0, __shfl(accR[0], srcA), __shfl(accR[1], srcA), __shfl(accI[0], srcA), __shfl(accI[1], srcA));
    PUTW(1, __shfl(accR[2], srcA), __shfl(accR[3], srcA), __shfl(accI[2], srcA), __shfl(accI[3], srcA));
    PUTW(2, __shfl(accR[0], srcB), __shfl(accR[1], srcB), __shfl(accI[0], srcB), __shfl(accI[1], srcB));
    PUTW(3, __shfl(accR[2], srcB), __shfl(accR[3], srcB), __shfl(accI[2], srcB), __shfl(accI[3], srcB));
  };

  // steady state entering iter t: tiles <= t resident; DMA of t+1, t+2 in flight (8 ops)
#pragma unroll 3
  for (int t = 1; t <= kCL - 4; ++t) {   // t = 1..12, issues 4..15
    stepMFMA(t % 3);
    repack();
    issueStep(t + 3);                               // -> slot t%3 (tile t just consumed)
    asm volatile("s_waitcnt vmcnt(8)" ::: "memory");  // tile t+1 resident
    splitA((t + 1) % 3);                            // off-critical-path pre-split
  }
  // t = 13
  stepMFMA(1);
  repack();
  asm volatile("s_waitcnt vmcnt(4)" ::: "memory");  // tile 14 resident
  splitA(2);
  // t = 14
  stepMFMA(2);
  repack();
  asm volatile("s_waitcnt vmcnt(0)" ::: "memory");  // tile 15 resident
  splitA(0);
  // t = 15 (final; acc = P_g, vnr/vni = v_g)
  stepMFMA(0);

  // ---- store P_g (row-major [row][col] float2) from C-layout, and v_g ----
  {
    float* pd = Pg + (size_t)ck * 512;
#pragma unroll
    for (int r = 0; r < 4; ++r) {
      *(float2*)(pd + (4 * q + r) * 32 + j * 2) = make_float2(accR[r], accI[r]);
    }
  }
  if (kq == 0) *(float2*)(Vg + (size_t)ck * 32 + jv * 2) = make_float2(vnr, vni);
}

// ---------------- Phase 2: sequential carry scan (1 chain per wave, 64-lane matvec) ----------
constexpr int kD2 = 4;
__global__ __launch_bounds__(64, 1) void pscan_phase2(
    const float* __restrict__ Pg, const float* __restrict__ Vg, float* __restrict__ Sg) {
  const int lane = threadIdx.x;
  const int kq = lane >> 4, i = lane & 15;
  const int chain = blockIdx.x;

  const float* pB = Pg + (size_t)chain * kG * 512 + (size_t)i * 32 + 8 * kq;
  const float* vB = Vg + (size_t)chain * kG * 32 + 2 * i;
  float* sB = Sg + (size_t)chain * kG * 32 + 2 * i;

  float4 bP0[kD2], bP1[kD2]; float2 bV[kD2];
#pragma unroll
  for (int d = 0; d < kD2; ++d) {
    bP0[d] = *(const float4*)(pB + (size_t)d * 512);
    bP1[d] = *(const float4*)(pB + (size_t)d * 512 + 4);
    bV[d] = *(const float2*)(vB + (size_t)d * 32);
  }

  float ykr[4] = {0, 0, 0, 0}, yki[4] = {0, 0, 0, 0};
  float ynr = 0.f, yni = 0.f;

  for (int gg = 0; gg < kG; gg += kD2) {
#pragma unroll
    for (int d = 0; d < kD2; ++d) {
      if (kq == 0) *(float2*)(sB + (size_t)(gg + d) * 32) = make_float2(ynr, yni);  // S_{g-1}
      const float4 p0 = bP0[d], p1 = bP1[d];
      const float2 vv = bV[d];
      const int gn = gg + d + kD2;
      if (gn < kG) {
        bP0[d] = *(const float4*)(pB + (size_t)gn * 512);
        bP1[d] = *(const float4*)(pB + (size_t)gn * 512 + 4);
        bV[d] = *(const float2*)(vB + (size_t)gn * 32);
      }
      float tr = p0.x * ykr[0] - p0.y * yki[0] + p0.z * ykr[1] - p0.w * yki[1]
               + p1.x * ykr[2] - p1.y * yki[2] + p1.z * ykr[3] - p1.w * yki[3];
      float ti = p0.x * yki[0] + p0.y * ykr[0] + p0.z * yki[1] + p0.w * ykr[1]
               + p1.x * yki[2] + p1.y * ykr[2] + p1.z * yki[3] + p1.w * ykr[3];
      tr = redq(tr); ti = redq(ti);
      ynr = tr + vv.x;
      yni = ti + vv.y;
#pragma unroll
      for (int kk = 0; kk < 4; ++kk) {
        const int src = (lane & 48) | (4 * kq + kk);
        ykr[kk] = __shfl(ynr, src);
        yki[kk] = __shfl(yni, src);
      }
    }
  }
}

// ---------------- Phase 3: replay chunks from carries (64-lane matvec, high occupancy) ----------
__global__ __launch_bounds__(256, 4) void pscan_phase3(
    const float* __restrict__ Ar, const float* __restrict__ Ai,
    const float* __restrict__ Xr, const float* __restrict__ Xi,
    const float* __restrict__ Sg, float* __restrict__ out) {
  const int lane = threadIdx.x & 63;
  const int wid = threadIdx.x >> 6;
  const int kq = lane >> 4, i = lane & 15;
  const int ck = blockIdx.x * 4 + wid;
  const int chain = ck >> 6, g = ck & 63;
  const int bb = chain >> 5, cc = chain & 31;
  const int t0 = g * kCL;

  const size_t aBase = ((size_t)(bb * kLtot + t0) * kC + cc) * 256 + (size_t)i * 16 + 4 * kq;
  const size_t xBase = ((size_t)(bb * kLtot + t0) * kC + cc) * 16 + i;
  const size_t aStep = (size_t)kC * 256, xStep = (size_t)kC * 16;
  float* outB = out + ((size_t)(bb * kLtot + t0) * kC + cc) * 32 + 2 * i;

  float ynr, yni, ykr[4], yki[4];
  {
    const float2 s = *(const float2*)(Sg + (size_t)ck * 32 + 2 * i);
    ynr = s.x; yni = s.y;
  }
#pragma unroll
  for (int kk = 0; kk < 4; ++kk) {
    const int src = (lane & 48) | (4 * kq + kk);
    ykr[kk] = __shfl(ynr, src);
    yki[kk] = __shfl(yni, src);
  }

  float4 aR[2], aI[2]; float2 xx[2];
  auto loadT = [&](int t, int s) {
    aR[s] = *(const float4*)(Ar + aBase + (size_t)t * aStep);
    aI[s] = *(const float4*)(Ai + aBase + (size_t)t * aStep);
    xx[s].x = Xr[xBase + (size_t)t * xStep];
    xx[s].y = Xi[xBase + (size_t)t * xStep];
  };
  loadT(0, 0);
  loadT(1, 1);

  for (int t = 0; t < kCL; ++t) {
    const int s = t & 1;
    const float4 a4 = aR[s], b4 = aI[s];
    const float2 xv = xx[s];
    float tr = a4.x * ykr[0] - b4.x * yki[0] + a4.y * ykr[1] - b4.y * yki[1]
             + a4.z * ykr[2] - b4.z * yki[2] + a4.w * ykr[3] - b4.w * yki[3];
    float ti = a4.x * yki[0] + b4.x * ykr[0] + a4.y * yki[1] + b4.y * ykr[1]
             + a4.z * yki[2] + b4.z * ykr[2] + a4.w * yki[3] + b4.w * ykr[3];
    tr = redq(tr); ti = redq(ti);
    ynr = tr + xv.x;
    yni = ti + xv.y;
    if (kq == 0) *(float2*)(outB + (size_t)t * (kC * 32)) = make_float2(ynr, yni);
    const int tn = t + 2;
    if (tn < kCL) loadT(tn, s);
#pragma unroll
    for (int kk = 0; kk < 4; ++kk) {
      const int src = (lane & 48) | (4 * kq + kk);
      ykr[kk] = __shfl(ynr, src);
      yki[kk] = __shfl(yni, src);
    }
  }
}

extern "C" void kernel_launch(void* const* d_in, const int* in_sizes, int n_in,
                              void* d_out, int out_size, void* d_ws, size_t ws_size,
                              hipStream_t stream) {
  const float* Ar = (const float*)d_in[0];
  const float* Ai = (const float*)d_in[1];
  const float* Xr = (const float*)d_in[2];
  const float* Xi = (const float*)d_in[3];
  // Workspace: Pg 8MB + Vg 512KB + Sg 512KB = 9MB
  float* Pg = (float*)d_ws;
  float* Vg = Pg + (size_t)kNCK * 512;
  float* Sg = Vg + (size_t)kNCK * 32;

  pscan_phase1<<<kNCK / 4, 256, 0, stream>>>(Ar, Ai, Xr, Xi, Pg, Vg);
  pscan_phase2<<<kNCH, 64, 0, stream>>>(Pg, Vg, Sg);
  pscan_phase3<<<kNCK / 4, 256, 0, stream>>>(Ar, Ai, Xr, Xi, Sg, (float*)d_out);
}